// Round 3
// baseline (380.087 us; speedup 1.0000x reference)
//
#include <hip/hip_runtime.h>

#define KNEIGH 16
#define FDIM   128

// Native clang vector type: __builtin_nontemporal_store rejects HIP's
// float4 class type, but accepts ext_vector_type.
typedef float f32x4 __attribute__((ext_vector_type(4)));

// One wave (64 lanes) per batch row, split into half-waves: lanes 0-31 take
// even neighbors, lanes 32-63 odd neighbors; each lane loads a float4 slice,
// so one global_load_dwordx4 covers TWO 512 B feature rows (8 gathers/row).
//
// Control path is fully scalarized: row is wave-uniform (readfirstlane), so
// the 16 weights + 16 indices are loaded via s_load into SGPRs. No
// ds_bpermute broadcasts, no divergent lane<16 loads -- all 8 gather
// addresses are ready after a single lgkmcnt wait, letting the compiler
// issue the gathers back-to-back for maximum loads-in-flight.
__global__ __launch_bounds__(256) void WeightedAggregator_89489938580183_kernel(
    const float* __restrict__ features,   // [N, 128]
    const float* __restrict__ neigh_w,    // [B, 16]
    const int*   __restrict__ neigh_idx,  // [B, 16] (int32 per harness)
    float*       __restrict__ out,        // [B, 128]
    int batch) {

    const int lane = threadIdx.x & 63;
    int row = blockIdx.x * (blockDim.x >> 6) + (threadIdx.x >> 6);
    if (row >= batch) return;
    row = __builtin_amdgcn_readfirstlane(row);   // provably wave-uniform

    // Scalar (SGPR) loads of this row's weight/index vectors.
    const float* wp = neigh_w   + (size_t)row * KNEIGH;
    const int*   ip = neigh_idx + (size_t)row * KNEIGH;
    float w[KNEIGH];
    int   idx[KNEIGH];
    #pragma unroll
    for (int k = 0; k < KNEIGH; ++k) { w[k] = wp[k]; idx[k] = ip[k]; }

    // Uniform weight sum + normalization (match reference semantics).
    float s = w[0];
    #pragma unroll
    for (int k = 1; k < KNEIGH; ++k) s += w[k];
    const float inv = 1.0f / s;

    const int half = lane >> 5;   // 0: even neighbors, 1: odd neighbors
    const int sub  = lane & 31;   // float4 column quad owned

    // Dual accumulators break the serial FMA dependence chain.
    f32x4 acc0 = (f32x4)(0.0f);
    f32x4 acc1 = (f32x4)(0.0f);

    #pragma unroll
    for (int kk = 0; kk < KNEIGH; kk += 4) {
        const int   iA = half ? idx[kk + 1] : idx[kk];
        const float wA = (half ? w[kk + 1] : w[kk]) * inv;
        const int   iB = half ? idx[kk + 3] : idx[kk + 2];
        const float wB = (half ? w[kk + 3] : w[kk + 2]) * inv;

        // 32-bit zext offsets: SGPR base + VGPR voffset addressing,
        // no per-neighbor 64-bit address arithmetic.
        const f32x4 fA = ((const f32x4*)features)[((unsigned)iA << 5) + sub];
        const f32x4 fB = ((const f32x4*)features)[((unsigned)iB << 5) + sub];

        acc0 += wA * fA;
        acc1 += wB * fB;
    }

    f32x4 acc = acc0 + acc1;

    // Fold odd-neighbor partials (lanes 32-63) into lanes 0-31.
    acc.x += __shfl_xor(acc.x, 32);
    acc.y += __shfl_xor(acc.y, 32);
    acc.z += __shfl_xor(acc.z, 32);
    acc.w += __shfl_xor(acc.w, 32);

    // 32 lanes x 16 B = 512 B coalesced row write; non-temporal keeps the
    // write-once output stream from evicting feature rows in L2/L3.
    if (half == 0) {
        f32x4* dst = (f32x4*)(out + (size_t)row * FDIM) + sub;
        __builtin_nontemporal_store(acc, dst);
    }
}

extern "C" void kernel_launch(void* const* d_in, const int* in_sizes, int n_in,
                              void* d_out, int out_size, void* d_ws, size_t ws_size,
                              hipStream_t stream) {
    const float* features  = (const float*)d_in[0];
    const float* neigh_w   = (const float*)d_in[1];
    const int*   neigh_idx = (const int*)d_in[2];
    float*       out       = (float*)d_out;

    const int batch = in_sizes[1] / KNEIGH;      // 50000

    // 4 waves per 256-thread block, one wave per row.
    const int waves_per_block = 256 / 64;
    const int blocks = (batch + waves_per_block - 1) / waves_per_block;
    WeightedAggregator_89489938580183_kernel<<<blocks, 256, 0, stream>>>(
        features, neigh_w, neigh_idx, out, batch);
}

// Round 4
// 351.044 us; speedup vs baseline: 1.0827x; 1.0827x over previous
//
#include <hip/hip_runtime.h>

#define KNEIGH 16
#define FDIM   128

typedef float f32x4 __attribute__((ext_vector_type(4)));

// One HALF-WAVE (32 lanes) per batch row; each wave covers two consecutive
// rows (2r for lanes 0-31, 2r+1 for lanes 32-63). Each lane owns one float4
// (16 B) slice of the 512 B feature row, so every global_load_dwordx4
// fetches two full feature rows (1 KB/instr), 16 gathers per wave.
//
// - No cross-lane shuffles at all: each half-wave accumulates its own row.
// - Both rows' weights+indices are one contiguous 128 B block -> scalar
//   s_load into SGPRs; weight sums are uniform SALU-side per row.
// - Final store: 64 lanes x 16 B = 1 KB contiguous (rows 2r,2r+1 adjacent),
//   a single fully-coalesced store per wave.
__global__ __launch_bounds__(256) void WeightedAggregator_89489938580183_kernel(
    const float* __restrict__ features,   // [N, 128]
    const float* __restrict__ neigh_w,    // [B, 16]
    const int*   __restrict__ neigh_idx,  // [B, 16] (int32 per harness)
    float*       __restrict__ out,        // [B, 128]
    int batch) {

    const int lane = threadIdx.x & 63;
    int wid = blockIdx.x * (blockDim.x >> 6) + (threadIdx.x >> 6);
    int rowA = wid * 2;
    if (rowA >= batch) return;
    rowA = __builtin_amdgcn_readfirstlane(rowA);       // wave-uniform
    const int rowB = (rowA + 1 < batch) ? rowA + 1 : rowA;  // tail clamp

    // Scalar loads: two rows' weights / indices (contiguous when rowB=rowA+1).
    const float* wpA = neigh_w   + (size_t)rowA * KNEIGH;
    const float* wpB = neigh_w   + (size_t)rowB * KNEIGH;
    const int*   ipA = neigh_idx + (size_t)rowA * KNEIGH;
    const int*   ipB = neigh_idx + (size_t)rowB * KNEIGH;

    float wA[KNEIGH], wB[KNEIGH];
    int   iA[KNEIGH], iB[KNEIGH];
    #pragma unroll
    for (int k = 0; k < KNEIGH; ++k) {
        wA[k] = wpA[k]; wB[k] = wpB[k];
        iA[k] = ipA[k]; iB[k] = ipB[k];
    }

    // Uniform per-row weight sums -> per-row 1/sum.
    float sA = wA[0], sB = wB[0];
    #pragma unroll
    for (int k = 1; k < KNEIGH; ++k) { sA += wA[k]; sB += wB[k]; }
    const float invA = 1.0f / sA;
    const float invB = 1.0f / sB;

    const int half = lane >> 5;   // 0 -> rowA, 1 -> rowB
    const int sub  = lane & 31;   // float4 column quad owned
    const float inv = half ? invB : invA;

    // Dual accumulators break the serial FMA dependence chain.
    f32x4 acc0 = (f32x4)(0.0f);
    f32x4 acc1 = (f32x4)(0.0f);

    #pragma unroll
    for (int k = 0; k < KNEIGH; k += 2) {
        const int   i0 = half ? iB[k]     : iA[k];
        const int   i1 = half ? iB[k + 1] : iA[k + 1];
        const float w0 = (half ? wB[k]     : wA[k])     * inv;
        const float w1 = (half ? wB[k + 1] : wA[k + 1]) * inv;

        // 32-bit zext voffset: SGPR base + (idx*512B + sub*16B).
        const f32x4 f0 = ((const f32x4*)features)[((unsigned)i0 << 5) + sub];
        const f32x4 f1 = ((const f32x4*)features)[((unsigned)i1 << 5) + sub];

        acc0 += w0 * f0;
        acc1 += w1 * f1;
    }

    const f32x4 acc = acc0 + acc1;

    // 1 KB fully-coalesced wave store (rows 2r, 2r+1 contiguous).
    const int orow = rowA + half;
    if (orow < batch) {
        f32x4* dst = (f32x4*)(out + (size_t)orow * FDIM) + sub;
        *dst = acc;
    }
}

extern "C" void kernel_launch(void* const* d_in, const int* in_sizes, int n_in,
                              void* d_out, int out_size, void* d_ws, size_t ws_size,
                              hipStream_t stream) {
    const float* features  = (const float*)d_in[0];
    const float* neigh_w   = (const float*)d_in[1];
    const int*   neigh_idx = (const int*)d_in[2];
    float*       out       = (float*)d_out;

    const int batch = in_sizes[1] / KNEIGH;      // 50000

    // One wave per TWO rows; 4 waves per 256-thread block.
    const int rows_per_block = 2 * (256 / 64);
    const int blocks = (batch + rows_per_block - 1) / rows_per_block;
    WeightedAggregator_89489938580183_kernel<<<blocks, 256, 0, stream>>>(
        features, neigh_w, neigh_idx, out, batch);
}